// Round 6
// baseline (91.280 us; speedup 1.0000x reference)
//
#include <hip/hip_runtime.h>
#include <hip/hip_bf16.h>

#define Bn 16
#define Sn 2048
#define Hn 768
#define Dn 128
#define AT 8
#define IT 32
#define NSEG (Bn*AT*IT)      // 4096

typedef __attribute__((ext_vector_type(4))) float f32x4;
typedef __attribute__((ext_vector_type(4))) int   i32x4;
typedef __attribute__((ext_vector_type(8))) short bf16x8;
typedef __attribute__((ext_vector_type(4))) short s16x4;

__device__ __forceinline__ unsigned short f2bf(float f){
  __hip_bfloat16 h = __float2bfloat16(f);   // HW RNE
  return *reinterpret_cast<unsigned short*>(&h);
}

// ---- kernel 0: W transpose to bf16 [128][768] + zero the batch-done flags ----
__global__ __launch_bounds__(256) void k_prep(const float* __restrict__ W,
                                              unsigned short* __restrict__ Wt,
                                              int* __restrict__ flags){
  __shared__ float sT[64][65];
  const int tid = threadIdx.x;
  if (blockIdx.x == 0 && tid < Bn)
    __hip_atomic_store(&flags[tid], 0, __ATOMIC_RELAXED, __HIP_MEMORY_SCOPE_AGENT);
  const int k0 = (blockIdx.x % 12) * 64;
  const int d0 = (blockIdx.x / 12) * 64;
  const int rr = tid >> 4;          // 0..15
  const int cg = tid & 15;          // 0..15 -> 4 cols

  #pragma unroll
  for (int p = 0; p < 4; ++p){
    int k = rr + p*16;
    f32x4 v = *(const f32x4*)&W[(size_t)(k0 + k)*Dn + d0 + cg*4];
    sT[k][cg*4+0] = v[0]; sT[k][cg*4+1] = v[1];
    sT[k][cg*4+2] = v[2]; sT[k][cg*4+3] = v[3];
  }
  __syncthreads();
  #pragma unroll
  for (int p = 0; p < 4; ++p){
    int d = rr + p*16;
    s16x4 t;
    #pragma unroll
    for (int j = 0; j < 4; ++j) t[j] = (short)f2bf(sT[cg*4+j][d]);
    *(s16x4*)&Wt[(size_t)(d0 + d)*Hn + k0 + cg*4] = t;
  }
}

// ---- fused kernel: GEMM tile (all 512 WGs) -> flag release -> scan (WGs 0..255) ----
// GEMM: BM=64, BN=128, BK=64 (R3 structure — best measured). 48KB LDS -> 3 WG/CU
// capacity -> all 512 WGs co-resident -> flag spin cannot deadlock.
__global__ __launch_bounds__(256) void k_fused(const float* __restrict__ X,
        const unsigned short* __restrict__ Wt, const float* __restrict__ bias,
        const int* __restrict__ attr, const int* __restrict__ item,
        float* __restrict__ Hout, float* __restrict__ pooled,
        float* __restrict__ empty, int* __restrict__ flags){
  __shared__ union {
    struct { unsigned char a[2][64*128]; unsigned char b[2][128*128]; } g;  // 48 KB
    struct { float ssum[4][IT][64]; int slist[4][512]; int scnt[IT]; } s;   // 40.1 KB
  } u;

  const int tid  = threadIdx.x;
  const int lane = tid & 63;
  const int wave = tid >> 6;
  const int tile = blockIdx.x;
  const int m0 = tile * 64;

  { // ================= GEMM phase =================
    const int ar = tid >> 2, akq = tid & 3;    // A: row, k-quarter
    const int bc = tid >> 1, bkh = tid & 1;    // B: col, k-half
    const float*          Ap = X  + (size_t)(m0 + ar)*Hn + akq*4;
    const unsigned short* Bp = Wt + (size_t)bc*Hn + bkh*32;

    int aw[4], bw[4];
    #pragma unroll
    for (int c=0;c<4;c++) aw[c] = ar*128 + ((akq*8 + c*32) ^ ((ar&7)<<4));
    #pragma unroll
    for (int c=0;c<4;c++) bw[c] = bc*128 + ((bkh*64 + c*16) ^ ((bc&7)<<4));

    int abase[4], aswz[4];
    #pragma unroll
    for (int mi=0;mi<4;mi++){
      int row = mi*16 + (lane&15);
      abase[mi] = row*128; aswz[mi] = (row&7)<<4;
    }
    int bbase[2], bswz[2];
    #pragma unroll
    for (int ni=0;ni<2;ni++){
      int col = wave*32 + ni*16 + (lane&15);
      bbase[ni] = col*128; bswz[ni] = (col&7)<<4;
    }
    const int kblk = (lane>>4)*16;

    f32x4 acc[4][2];
    #pragma unroll
    for (int mi=0;mi<4;mi++)
      #pragma unroll
      for (int ni=0;ni<2;ni++) acc[mi][ni] = (f32x4){0.f,0.f,0.f,0.f};

    f32x4 av[4]; i32x4 bv[4];
    #pragma unroll
    for (int c=0;c<4;c++) av[c] = *(const f32x4*)(Ap + c*16);
    #pragma unroll
    for (int c=0;c<4;c++) bv[c] = *(const i32x4*)(Bp + c*8);
    #pragma unroll
    for (int c=0;c<4;c++){
      s16x4 t;
      t[0]=(short)f2bf(av[c][0]); t[1]=(short)f2bf(av[c][1]);
      t[2]=(short)f2bf(av[c][2]); t[3]=(short)f2bf(av[c][3]);
      *(s16x4*)&u.g.a[0][aw[c]] = t;
    }
    #pragma unroll
    for (int c=0;c<4;c++) *(i32x4*)&u.g.b[0][bw[c]] = bv[c];
    __syncthreads();

    int cur = 0;
    for (int step=0; step<12; ++step){
      if (step < 11){
        #pragma unroll
        for (int c=0;c<4;c++) av[c] = *(const f32x4*)(Ap + (step+1)*64 + c*16);
        #pragma unroll
        for (int c=0;c<4;c++) bv[c] = *(const i32x4*)(Bp + (step+1)*64 + c*8);
      }
      #pragma unroll
      for (int ks=0; ks<2; ++ks){
        bf16x8 af[4], bfv[2];
        #pragma unroll
        for (int mi=0;mi<4;mi++)
          af[mi] = *(const bf16x8*)&u.g.a[cur][abase[mi] + ((ks*64 + kblk) ^ aswz[mi])];
        #pragma unroll
        for (int ni=0;ni<2;ni++)
          bfv[ni] = *(const bf16x8*)&u.g.b[cur][bbase[ni] + ((ks*64 + kblk) ^ bswz[ni])];
        #pragma unroll
        for (int mi=0;mi<4;mi++)
          #pragma unroll
          for (int ni=0;ni<2;ni++)
            acc[mi][ni] = __builtin_amdgcn_mfma_f32_16x16x32_bf16(af[mi], bfv[ni], acc[mi][ni], 0, 0, 0);
      }
      if (step < 11){
        #pragma unroll
        for (int c=0;c<4;c++){
          s16x4 t;
          t[0]=(short)f2bf(av[c][0]); t[1]=(short)f2bf(av[c][1]);
          t[2]=(short)f2bf(av[c][2]); t[3]=(short)f2bf(av[c][3]);
          *(s16x4*)&u.g.a[cur^1][aw[c]] = t;
        }
        #pragma unroll
        for (int c=0;c<4;c++) *(i32x4*)&u.g.b[cur^1][bw[c]] = bv[c];
      }
      __syncthreads();
      cur ^= 1;
    }

    // epilogue: C/D layout col=lane&15, row=(lane>>4)*4+r
    #pragma unroll
    for (int ni=0;ni<2;ni++){
      int col = wave*32 + ni*16 + (lane&15);
      float bb = bias[col];
      #pragma unroll
      for (int mi=0;mi<4;mi++){
        int row0 = m0 + mi*16 + (lane>>4)*4;
        #pragma unroll
        for (int r=0;r<4;r++)
          Hout[(size_t)(row0 + r)*Dn + col] = acc[mi][ni][r] + bb;
      }
    }
  }

  __syncthreads();          // drains vmcnt: all threads' h-stores complete; LDS reusable
  if (tid == 0)             // publish: release covers this WG's h writes (L2 writeback)
    __hip_atomic_fetch_add(&flags[tile >> 5], 1, __ATOMIC_RELEASE, __HIP_MEMORY_SCOPE_AGENT);

  if (tile >= Bn*AT*2) return;   // WGs 256..511 done

  // ================= scan phase (WG = (b*8+a)*2+dh) =================
  const int wg  = tile;
  const int dh  = wg & 1;
  const int a   = (wg >> 1) & 7;
  const int b   = wg >> 4;
  const int wv  = wave;

  #pragma unroll
  for (int i = 0; i < IT; ++i) u.s.ssum[wv][i][lane] = 0.f;
  if (tid < IT) u.s.scnt[tid] = 0;

  // build ordered match list (no h dependency — overlaps other WGs' GEMM tails)
  const int tok0 = wv * 512;
  const int gbase = b * Sn;
  int nm = 0;
  #pragma unroll
  for (int g = 0; g < 8; ++g){
    int tok = tok0 + g*64 + lane;
    int avv = attr[gbase + tok], ivv = item[gbase + tok];
    bool m = (avv == a+1) && (ivv >= 1) && (ivv <= IT);
    unsigned long long mask = __ballot(m);
    int pos = nm + __popcll(mask & ((1ull << lane) - 1ull));
    if (m) u.s.slist[wv][pos] = ((ivv-1) << 16) | tok;
    nm += __popcll(mask);
  }
  __syncthreads();   // scnt zeros + lists visible

  for (int e = lane; e < nm; e += 64) atomicAdd(&u.s.scnt[u.s.slist[wv][e] >> 16], 1);

  // wait until all 32 GEMM tiles of batch b have published their h rows
  if (tid == 0){
    while (__hip_atomic_load(&flags[b], __ATOMIC_ACQUIRE, __HIP_MEMORY_SCOPE_AGENT) < 32)
      __builtin_amdgcn_s_sleep(2);
  }
  __syncthreads();
  // per-wave acquire so every wave's subsequent h reads are ordered/invalidated
  (void)__hip_atomic_load(&flags[b], __ATOMIC_ACQUIRE, __HIP_MEMORY_SCOPE_AGENT);

  const float* hb = Hout + (size_t)b*Sn*Dn + dh*64 + lane;
  int e = 0;
  for (; e + 8 <= nm; e += 8){
    int idx[8]; float v[8];
    #pragma unroll
    for (int j=0;j<8;j++) idx[j] = u.s.slist[wv][e+j];
    #pragma unroll
    for (int j=0;j<8;j++) v[j] = hb[(size_t)(idx[j] & 0xffff)*Dn];
    #pragma unroll
    for (int j=0;j<8;j++) u.s.ssum[wv][idx[j]>>16][lane] += v[j];
  }
  for (; e < nm; ++e){
    int idx = u.s.slist[wv][e];
    u.s.ssum[wv][idx>>16][lane] += hb[(size_t)(idx & 0xffff)*Dn];
  }
  __syncthreads();

  float* outp = pooled + (size_t)(b*AT + a)*IT*Dn + dh*64;
  for (int o = tid; o < IT*64; o += 256){
    int i = o >> 6, d = o & 63;
    float s = u.s.ssum[0][i][d] + u.s.ssum[1][i][d] + u.s.ssum[2][i][d] + u.s.ssum[3][i][d];
    int cnt = u.s.scnt[i];
    outp[i*Dn + d] = s / (float)(cnt > 0 ? cnt : 1);
  }
  if (dh == 0 && tid < IT)
    empty[(b*AT + a)*IT + tid] = (u.s.scnt[tid] == 0) ? 1.f : 0.f;
}

extern "C" void kernel_launch(void* const* d_in, const int* in_sizes, int n_in,
                              void* d_out, int out_size, void* d_ws, size_t ws_size,
                              hipStream_t stream) {
  const float* hidden = (const float*)d_in[1];
  const int*   attr   = (const int*)  d_in[2];
  const int*   item   = (const int*)  d_in[3];
  const float* W      = (const float*)d_in[4];
  const float* bias   = (const float*)d_in[5];

  float* pooled = (float*)d_out;
  float* empty  = pooled + (size_t)NSEG*Dn;          // +524288
  float* Hout   = empty  + NSEG;                     // +4096

  unsigned short* Wt = (unsigned short*)d_ws;        // 196608 B
  int* flags = (int*)((char*)d_ws + 196608);         // 16 ints, zeroed by k_prep

  k_prep<<<24, 256, 0, stream>>>(W, Wt, flags);
  k_fused<<<(Bn*Sn)/64, 256, 0, stream>>>(hidden, Wt, bias, attr, item,
                                          Hout, pooled, empty, flags);
}

// Round 7
// 68.279 us; speedup vs baseline: 1.3369x; 1.3369x over previous
//
#include <hip/hip_runtime.h>
#include <hip/hip_bf16.h>

#define Bn 16
#define Sn 2048
#define Hn 768
#define Dn 128
#define AT 8
#define IT 32
#define NSEG (Bn*AT*IT)      // 4096

typedef __attribute__((ext_vector_type(4))) float f32x4;
typedef __attribute__((ext_vector_type(4))) int   i32x4;
typedef __attribute__((ext_vector_type(8))) short bf16x8;
typedef __attribute__((ext_vector_type(4))) short s16x4;

__device__ __forceinline__ unsigned short f2bf(float f){
  __hip_bfloat16 h = __float2bfloat16(f);   // HW RNE
  return *reinterpret_cast<unsigned short*>(&h);
}

// ---- kernel 0: W [768][128] f32 -> Wt [128][768] bf16, LDS-tiled transpose ----
__global__ __launch_bounds__(256) void k_prep(const float* __restrict__ W,
                                              unsigned short* __restrict__ Wt){
  __shared__ float sT[64][65];
  const int tid = threadIdx.x;
  const int k0 = (blockIdx.x % 12) * 64;
  const int d0 = (blockIdx.x / 12) * 64;
  const int rr = tid >> 4;          // 0..15
  const int cg = tid & 15;          // 0..15 -> 4 cols

  #pragma unroll
  for (int p = 0; p < 4; ++p){
    int k = rr + p*16;
    f32x4 v = *(const f32x4*)&W[(size_t)(k0 + k)*Dn + d0 + cg*4];
    sT[k][cg*4+0] = v[0]; sT[k][cg*4+1] = v[1];
    sT[k][cg*4+2] = v[2]; sT[k][cg*4+3] = v[3];
  }
  __syncthreads();
  #pragma unroll
  for (int p = 0; p < 4; ++p){
    int d = rr + p*16;
    s16x4 t;
    #pragma unroll
    for (int j = 0; j < 4; ++j) t[j] = (short)f2bf(sT[cg*4+j][d]);
    *(s16x4*)&Wt[(size_t)(d0 + d)*Hn + k0 + cg*4] = t;
  }
}

// ---- kernel 1: h = X @ W + b — LDS-FREE streaming MFMA ----
// BM=64, grid 512, 4 waves split 2m x 2n. A-fragments: global f32 -> reg -> cvt
// bf16 (16 rows x 64B coalesced per inst, same pattern as LDS staging had).
// B-fragments: 16B loads from L2-resident Wt[col][k]. Zero barriers, zero LDS:
// no vmcnt(0) drain anywhere in the loop — waves free-run, compiler pipelines.
__global__ __launch_bounds__(256) void k_gemm(const float* __restrict__ X,
        const unsigned short* __restrict__ Wt, const float* __restrict__ bias,
        float* __restrict__ Hout){
  const int tid  = threadIdx.x;
  const int lane = tid & 63;
  const int wave = tid >> 6;
  const int wm   = wave >> 1;        // 0..1 -> row half
  const int wn   = wave & 1;         // 0..1 -> col half
  const int m0   = blockIdx.x * 64;
  const int r16  = lane & 15;
  const int kg   = lane >> 4;        // 0..3: k-subchunk of 8 elems

  // A rows: m0 + wm*32 + mi*16 + r16 ; k offset kg*8
  const float* Ap[2];
  #pragma unroll
  for (int mi=0;mi<2;mi++)
    Ap[mi] = X + (size_t)(m0 + wm*32 + mi*16 + r16)*Hn + kg*8;
  // B cols: wn*64 + ni*16 + r16 ; same k offset
  const unsigned short* Bp[4];
  #pragma unroll
  for (int ni=0;ni<4;ni++)
    Bp[ni] = Wt + (size_t)(wn*64 + ni*16 + r16)*Hn + kg*8;

  f32x4 acc[2][4];
  #pragma unroll
  for (int mi=0;mi<2;mi++)
    #pragma unroll
    for (int ni=0;ni<4;ni++) acc[mi][ni] = (f32x4){0.f,0.f,0.f,0.f};

  #pragma unroll 4
  for (int step=0; step<24; ++step){
    const int koff = step*32;
    bf16x8 a[2], b[4];
    #pragma unroll
    for (int mi=0;mi<2;mi++){
      f32x4 lo = *(const f32x4*)(Ap[mi] + koff);
      f32x4 hi = *(const f32x4*)(Ap[mi] + koff + 4);
      bf16x8 t;
      t[0]=(short)f2bf(lo[0]); t[1]=(short)f2bf(lo[1]);
      t[2]=(short)f2bf(lo[2]); t[3]=(short)f2bf(lo[3]);
      t[4]=(short)f2bf(hi[0]); t[5]=(short)f2bf(hi[1]);
      t[6]=(short)f2bf(hi[2]); t[7]=(short)f2bf(hi[3]);
      a[mi] = t;
    }
    #pragma unroll
    for (int ni=0;ni<4;ni++) b[ni] = *(const bf16x8*)(Bp[ni] + koff);
    #pragma unroll
    for (int mi=0;mi<2;mi++)
      #pragma unroll
      for (int ni=0;ni<4;ni++)
        acc[mi][ni] = __builtin_amdgcn_mfma_f32_16x16x32_bf16(a[mi], b[ni], acc[mi][ni], 0, 0, 0);
  }

  // epilogue: C/D layout col=lane&15, row=(lane>>4)*4+r  (m89-verified)
  #pragma unroll
  for (int ni=0;ni<4;ni++){
    int col = wn*64 + ni*16 + r16;
    float bb = bias[col];
    #pragma unroll
    for (int mi=0;mi<2;mi++){
      int row0 = m0 + wm*32 + mi*16 + kg*4;
      #pragma unroll
      for (int r=0;r<4;r++)
        Hout[(size_t)(row0 + r)*Dn + col] = acc[mi][ni][r] + bb;
    }
  }
}

// ---- kernel 2: per-(batch,attr,dim-half) segment mean -> pooled + empty ----
__global__ __launch_bounds__(256) void k_scan(const int* __restrict__ attr,
        const int* __restrict__ item, const float* __restrict__ Hsrc,
        float* __restrict__ pooled, float* __restrict__ empty){
  __shared__ float ssum[4][IT][64];   // 32 KB, one slab per wave
  __shared__ int   slist[4][512];     // 8 KB ordered match lists
  __shared__ int   scnt[IT];

  const int wg  = blockIdx.x;        // (b*8 + a)*2 + dh
  const int dh  = wg & 1;
  const int a   = (wg >> 1) & 7;
  const int b   = wg >> 4;
  const int tid = threadIdx.x;       // 0..255
  const int wv  = tid >> 6;
  const int lane = tid & 63;

  #pragma unroll
  for (int i = 0; i < IT; ++i) ssum[wv][i][lane] = 0.f;
  if (tid < IT) scnt[tid] = 0;

  const int tok0 = wv * 512;
  const int gbase = b * Sn;
  int nm = 0;
  #pragma unroll
  for (int g = 0; g < 8; ++g){
    int tok = tok0 + g*64 + lane;
    int avv = attr[gbase + tok], ivv = item[gbase + tok];
    bool m = (avv == a+1) && (ivv >= 1) && (ivv <= IT);
    unsigned long long mask = __ballot(m);
    int pos = nm + __popcll(mask & ((1ull << lane) - 1ull));
    if (m) slist[wv][pos] = ((ivv-1) << 16) | tok;
    nm += __popcll(mask);
  }
  __syncthreads();   // scnt zeros visible

  for (int e = lane; e < nm; e += 64) atomicAdd(&scnt[slist[wv][e] >> 16], 1);

  const float* hb = Hsrc + (size_t)b*Sn*Dn + dh*64 + lane;
  int e = 0;
  for (; e + 8 <= nm; e += 8){
    int idx[8]; float v[8];
    #pragma unroll
    for (int j=0;j<8;j++) idx[j] = slist[wv][e+j];
    #pragma unroll
    for (int j=0;j<8;j++) v[j] = hb[(size_t)(idx[j] & 0xffff)*Dn];
    #pragma unroll
    for (int j=0;j<8;j++) ssum[wv][idx[j]>>16][lane] += v[j];
  }
  for (; e < nm; ++e){
    int idx = slist[wv][e];
    ssum[wv][idx>>16][lane] += hb[(size_t)(idx & 0xffff)*Dn];
  }
  __syncthreads();

  float* outp = pooled + (size_t)(b*AT + a)*IT*Dn + dh*64;
  for (int o = tid; o < IT*64; o += 256){
    int i = o >> 6, d = o & 63;
    float s = ssum[0][i][d] + ssum[1][i][d] + ssum[2][i][d] + ssum[3][i][d];
    int cnt = scnt[i];
    outp[i*Dn + d] = s / (float)(cnt > 0 ? cnt : 1);
  }
  if (dh == 0 && tid < IT)
    empty[(b*AT + a)*IT + tid] = (scnt[tid] == 0) ? 1.f : 0.f;
}

extern "C" void kernel_launch(void* const* d_in, const int* in_sizes, int n_in,
                              void* d_out, int out_size, void* d_ws, size_t ws_size,
                              hipStream_t stream) {
  const float* hidden = (const float*)d_in[1];
  const int*   attr   = (const int*)  d_in[2];
  const int*   item   = (const int*)  d_in[3];
  const float* W      = (const float*)d_in[4];
  const float* bias   = (const float*)d_in[5];

  float* pooled = (float*)d_out;
  float* empty  = pooled + (size_t)NSEG*Dn;          // +524288
  float* Hout   = empty  + NSEG;                     // +4096

  unsigned short* Wt = (unsigned short*)d_ws;

  k_prep<<<24, 256, 0, stream>>>(W, Wt);
  k_gemm<<<(Bn*Sn)/64, 256, 0, stream>>>(hidden, Wt, bias, Hout);
  k_scan<<<Bn*AT*2, 256, 0, stream>>>(attr, item, Hout, pooled, empty);
}

// Round 8
// 53.400 us; speedup vs baseline: 1.7094x; 1.2787x over previous
//
#include <hip/hip_runtime.h>
#include <hip/hip_bf16.h>

#define Bn 16
#define Sn 2048
#define Hn 768
#define Dn 128
#define AT 8
#define IT 32
#define NSEG (Bn*AT*IT)      // 4096

typedef __attribute__((ext_vector_type(4))) float f32x4;
typedef __attribute__((ext_vector_type(4))) int   i32x4;
typedef __attribute__((ext_vector_type(8))) short bf16x8;
typedef __attribute__((ext_vector_type(4))) short s16x4;

__device__ __forceinline__ unsigned short f2bf(float f){
  __hip_bfloat16 h = __float2bfloat16(f);   // HW RNE
  return *reinterpret_cast<unsigned short*>(&h);
}

__device__ __forceinline__ void dma16(const float* g, const float* l){
  __builtin_amdgcn_global_load_lds(
      (const __attribute__((address_space(1))) unsigned int*)g,
      (__attribute__((address_space(3))) unsigned int*)l, 16, 0, 0);
}

// ---- kernel 0: W [768][128] f32 -> Wt [128][768] bf16, LDS-tiled transpose ----
__global__ __launch_bounds__(256) void k_prep(const float* __restrict__ W,
                                              unsigned short* __restrict__ Wt){
  __shared__ float sT[64][65];
  const int tid = threadIdx.x;
  const int k0 = (blockIdx.x % 12) * 64;
  const int d0 = (blockIdx.x / 12) * 64;
  const int rr = tid >> 4;          // 0..15
  const int cg = tid & 15;          // 0..15 -> 4 cols

  #pragma unroll
  for (int p = 0; p < 4; ++p){
    int k = rr + p*16;
    f32x4 v = *(const f32x4*)&W[(size_t)(k0 + k)*Dn + d0 + cg*4];
    sT[k][cg*4+0] = v[0]; sT[k][cg*4+1] = v[1];
    sT[k][cg*4+2] = v[2]; sT[k][cg*4+3] = v[3];
  }
  __syncthreads();
  #pragma unroll
  for (int p = 0; p < 4; ++p){
    int d = rr + p*16;
    s16x4 t;
    #pragma unroll
    for (int j = 0; j < 4; ++j) t[j] = (short)f2bf(sT[cg*4+j][d]);
    *(s16x4*)&Wt[(size_t)(d0 + d)*Hn + k0 + cg*4] = t;
  }
}

// ---- kernel 1: h = X @ W + b ----
// A: f32 tile 64x64 DMA'd via global_load_lds into triple-buffered LDS
//    (linear dest = conflict-free writes; inverse-swizzled SOURCE + XOR-swizzled
//    ds_read_b128: slot' = slot ^ (row&15) -> 4 lanes/slot on reads).
// B: direct 16B loads from L2-resident Wt (R7: these were never the problem).
// Sync: counted vmcnt(4) + raw s_barrier; loads NEVER drain to 0 in the loop.
// Per step ISA order (pinned by sched_barrier walls): [B-loads s][DMA s+2][compute].
// Compiler's own wait for B = vmcnt(4) (FIFO) -> retires DMA for s+1 exactly.
__global__ __launch_bounds__(256) void k_gemm(const float* __restrict__ X,
        const unsigned short* __restrict__ Wt, const float* __restrict__ bias,
        float* __restrict__ Hout){
  __shared__ float sA[3][64*64];     // 3 x 16KB
  const int tid  = threadIdx.x;
  const int lane = tid & 63;
  const int wave = tid >> 6;
  const int wm = wave >> 1, wn = wave & 1;
  const int m0 = blockIdx.x * 64;
  const int r16 = lane & 15, kg = lane >> 4;

  // DMA source geometry: chunk C = wave*256 + i*64 + lane -> LDS (row=C>>4, slot'=C&15)
  // source slot = slot' ^ (row&15)  (inverse swizzle; XOR is an involution)
  int drow[4], dslot[4];
  #pragma unroll
  for (int i=0;i<4;i++){
    int C = wave*256 + i*64 + lane;
    drow[i]  = C >> 4;
    dslot[i] = (C & 15) ^ (drow[i] & 15);
  }

  // B pointers: col = wn*64 + ni*16 + r16, k-base kg*8
  const unsigned short* Bp[4];
  #pragma unroll
  for (int ni=0;ni<4;ni++)
    Bp[ni] = Wt + (size_t)(wn*64 + ni*16 + r16)*Hn + kg*8;

  // A-frag read offsets (floats): row*64 + (slot ^ r16)*4, slot = ks*8+kg*2+sub
  int aoff[2][2][2];
  #pragma unroll
  for (int mi=0;mi<2;mi++)
    #pragma unroll
    for (int ks=0;ks<2;ks++)
      #pragma unroll
      for (int sub=0;sub<2;sub++)
        aoff[mi][ks][sub] = (wm*32 + mi*16 + r16)*64 + (((ks*8 + kg*2 + sub) ^ r16) << 2);

  f32x4 acc[2][4];
  #pragma unroll
  for (int mi=0;mi<2;mi++)
    #pragma unroll
    for (int ni=0;ni<4;ni++) acc[mi][ni] = (f32x4){0.f,0.f,0.f,0.f};

  auto stage = [&](int s, int buf){
    #pragma unroll
    for (int i=0;i<4;i++){
      const float* g = X + (size_t)(m0 + drow[i])*Hn + s*64 + dslot[i]*4;
      const float* l = &sA[buf][(wave*256 + i*64) << 2];   // wave-uniform base
      dma16(g, l);
    }
  };

  // prologue: tiles 0,1 in flight; wait tile 0 only (vmcnt(4) leaves tile 1 flying)
  stage(0, 0);
  stage(1, 1);
  asm volatile("s_waitcnt vmcnt(4)" ::: "memory");
  __builtin_amdgcn_s_barrier();
  __builtin_amdgcn_sched_barrier(0);

  #pragma unroll
  for (int s=0; s<12; ++s){
    const int buf = s % 3;
    // (1) B loads for this step — must be OLDER than the DMA in the vmem FIFO
    bf16x8 b[2][4];
    #pragma unroll
    for (int ks=0;ks<2;ks++)
      #pragma unroll
      for (int ni=0;ni<4;ni++)
        b[ks][ni] = *(const bf16x8*)(Bp[ni] + s*64 + ks*32);
    __builtin_amdgcn_sched_barrier(0);
    // (2) DMA tile s+2
    if (s < 10) stage(s+2, (s+2)%3);
    __builtin_amdgcn_sched_barrier(0);
    // (3) A frags from LDS f32 -> cvt bf16; then MFMA (k-order identical to R3)
    bf16x8 af[2][2];
    #pragma unroll
    for (int mi=0;mi<2;mi++)
      #pragma unroll
      for (int ks=0;ks<2;ks++){
        f32x4 lo = *(const f32x4*)&sA[buf][aoff[mi][ks][0]];
        f32x4 hi = *(const f32x4*)&sA[buf][aoff[mi][ks][1]];
        bf16x8 t;
        t[0]=(short)f2bf(lo[0]); t[1]=(short)f2bf(lo[1]);
        t[2]=(short)f2bf(lo[2]); t[3]=(short)f2bf(lo[3]);
        t[4]=(short)f2bf(hi[0]); t[5]=(short)f2bf(hi[1]);
        t[6]=(short)f2bf(hi[2]); t[7]=(short)f2bf(hi[3]);
        af[mi][ks] = t;
      }
    #pragma unroll
    for (int ks=0;ks<2;ks++)
      #pragma unroll
      for (int mi=0;mi<2;mi++)
        #pragma unroll
        for (int ni=0;ni<4;ni++)
          acc[mi][ni] = __builtin_amdgcn_mfma_f32_16x16x32_bf16(af[mi][ks], b[ks][ni], acc[mi][ni], 0, 0, 0);
    if (s < 11){
      asm volatile("s_waitcnt vmcnt(4)" ::: "memory");  // safety: ≤ DMA(s+2) outstanding
      __builtin_amdgcn_s_barrier();
      __builtin_amdgcn_sched_barrier(0);
    }
  }

  // epilogue: C/D layout col=lane&15, row=(lane>>4)*4+r  (m89-verified)
  #pragma unroll
  for (int ni=0;ni<4;ni++){
    int col = wn*64 + ni*16 + r16;
    float bb = bias[col];
    #pragma unroll
    for (int mi=0;mi<2;mi++){
      int row0 = m0 + wm*32 + mi*16 + kg*4;
      #pragma unroll
      for (int r=0;r<4;r++)
        Hout[(size_t)(row0 + r)*Dn + col] = acc[mi][ni][r] + bb;
    }
  }
}

// ---- kernel 2: per-(batch,attr,dim-half) segment mean -> pooled + empty ----
__global__ __launch_bounds__(256) void k_scan(const int* __restrict__ attr,
        const int* __restrict__ item, const float* __restrict__ Hsrc,
        float* __restrict__ pooled, float* __restrict__ empty){
  __shared__ float ssum[4][IT][64];   // 32 KB, one slab per wave
  __shared__ int   slist[4][512];     // 8 KB ordered match lists
  __shared__ int   scnt[IT];

  const int wg  = blockIdx.x;        // (b*8 + a)*2 + dh
  const int dh  = wg & 1;
  const int a   = (wg >> 1) & 7;
  const int b   = wg >> 4;
  const int tid = threadIdx.x;       // 0..255
  const int wv  = tid >> 6;
  const int lane = tid & 63;

  #pragma unroll
  for (int i = 0; i < IT; ++i) ssum[wv][i][lane] = 0.f;
  if (tid < IT) scnt[tid] = 0;

  const int tok0 = wv * 512;
  const int gbase = b * Sn;
  int nm = 0;
  #pragma unroll
  for (int g = 0; g < 8; ++g){
    int tok = tok0 + g*64 + lane;
    int avv = attr[gbase + tok], ivv = item[gbase + tok];
    bool m = (avv == a+1) && (ivv >= 1) && (ivv <= IT);
    unsigned long long mask = __ballot(m);
    int pos = nm + __popcll(mask & ((1ull << lane) - 1ull));
    if (m) slist[wv][pos] = ((ivv-1) << 16) | tok;
    nm += __popcll(mask);
  }
  __syncthreads();   // scnt zeros visible

  for (int e = lane; e < nm; e += 64) atomicAdd(&scnt[slist[wv][e] >> 16], 1);

  const float* hb = Hsrc + (size_t)b*Sn*Dn + dh*64 + lane;
  int e = 0;
  for (; e + 8 <= nm; e += 8){
    int idx[8]; float v[8];
    #pragma unroll
    for (int j=0;j<8;j++) idx[j] = slist[wv][e+j];
    #pragma unroll
    for (int j=0;j<8;j++) v[j] = hb[(size_t)(idx[j] & 0xffff)*Dn];
    #pragma unroll
    for (int j=0;j<8;j++) ssum[wv][idx[j]>>16][lane] += v[j];
  }
  for (; e < nm; ++e){
    int idx = slist[wv][e];
    ssum[wv][idx>>16][lane] += hb[(size_t)(idx & 0xffff)*Dn];
  }
  __syncthreads();

  float* outp = pooled + (size_t)(b*AT + a)*IT*Dn + dh*64;
  for (int o = tid; o < IT*64; o += 256){
    int i = o >> 6, d = o & 63;
    float s = ssum[0][i][d] + ssum[1][i][d] + ssum[2][i][d] + ssum[3][i][d];
    int cnt = scnt[i];
    outp[i*Dn + d] = s / (float)(cnt > 0 ? cnt : 1);
  }
  if (dh == 0 && tid < IT)
    empty[(b*AT + a)*IT + tid] = (scnt[tid] == 0) ? 1.f : 0.f;
}

extern "C" void kernel_launch(void* const* d_in, const int* in_sizes, int n_in,
                              void* d_out, int out_size, void* d_ws, size_t ws_size,
                              hipStream_t stream) {
  const float* hidden = (const float*)d_in[1];
  const int*   attr   = (const int*)  d_in[2];
  const int*   item   = (const int*)  d_in[3];
  const float* W      = (const float*)d_in[4];
  const float* bias   = (const float*)d_in[5];

  float* pooled = (float*)d_out;
  float* empty  = pooled + (size_t)NSEG*Dn;          // +524288
  float* Hout   = empty  + NSEG;                     // +4096

  unsigned short* Wt = (unsigned short*)d_ws;

  k_prep<<<24, 256, 0, stream>>>(W, Wt);
  k_gemm<<<(Bn*Sn)/64, 256, 0, stream>>>(hidden, Wt, bias, Hout);
  k_scan<<<Bn*AT*2, 256, 0, stream>>>(attr, item, Hout, pooled, empty);
}

// Round 9
// 40.727 us; speedup vs baseline: 2.2413x; 1.3112x over previous
//
#include <hip/hip_runtime.h>
#include <hip/hip_bf16.h>

#define Bn 16
#define Sn 2048
#define Hn 768
#define Dn 128
#define AT 8
#define IT 32
#define NSEG (Bn*AT*IT)      // 4096

typedef __attribute__((ext_vector_type(4))) float f32x4;
typedef __attribute__((ext_vector_type(4))) int   i32x4;
typedef __attribute__((ext_vector_type(8))) short bf16x8;
typedef __attribute__((ext_vector_type(4))) short s16x4;

__device__ __forceinline__ unsigned short f2bf(float f){
  __hip_bfloat16 h = __float2bfloat16(f);   // HW RNE
  return *reinterpret_cast<unsigned short*>(&h);
}

// ---- kernel 0: W [768][128] f32 -> Wt [128][768] bf16, LDS-tiled transpose ----
__global__ __launch_bounds__(256) void k_prep(const float* __restrict__ W,
                                              unsigned short* __restrict__ Wt){
  __shared__ float sT[64][65];
  const int tid = threadIdx.x;
  const int k0 = (blockIdx.x % 12) * 64;
  const int d0 = (blockIdx.x / 12) * 64;
  const int rr = tid >> 4;          // 0..15
  const int cg = tid & 15;          // 0..15 -> 4 cols

  #pragma unroll
  for (int p = 0; p < 4; ++p){
    int k = rr + p*16;
    f32x4 v = *(const f32x4*)&W[(size_t)(k0 + k)*Dn + d0 + cg*4];
    sT[k][cg*4+0] = v[0]; sT[k][cg*4+1] = v[1];
    sT[k][cg*4+2] = v[2]; sT[k][cg*4+3] = v[3];
  }
  __syncthreads();
  #pragma unroll
  for (int p = 0; p < 4; ++p){
    int d = rr + p*16;
    s16x4 t;
    #pragma unroll
    for (int j = 0; j < 4; ++j) t[j] = (short)f2bf(sT[cg*4+j][d]);
    *(s16x4*)&Wt[(size_t)(d0 + d)*Hn + k0 + cg*4] = t;
  }
}

// ---- kernel 1: h = X @ W + b  (bf16 MFMA 16x16x32) ----
// R3's verified LDS layout + fragment math, with:
//  * B in registers (full-step prefetch from L2-resident Wt) — no B LDS traffic
//  * raw s_barrier + lgkmcnt(0) only (NO vmcnt drain) -> A(s+2)/B(s+1) loads
//    stay in flight across the barrier (the __syncthreads vmcnt(0) drain was
//    why R4's deeper prefetch was neutral)
//  * A staging: thread=(row-group,k-chunk) -> each wave-instruction reads 4
//    contiguous 256B segments (vs 16 scattered 64B) for DRAM efficiency;
//    write phase covers all 32 banks exactly once per 16-lane row-phase.
__global__ __launch_bounds__(256) void k_gemm(const float* __restrict__ X,
        const unsigned short* __restrict__ Wt, const float* __restrict__ bias,
        float* __restrict__ Hout){
  __shared__ unsigned char sA[2][64*128];   // bf16, swizzled, 2 x 8 KB
  const int tid  = threadIdx.x;
  const int lane = tid & 63;
  const int wave = tid >> 6;
  const int m0   = blockIdx.x * 64;
  const int r16  = lane & 15, kg = lane >> 4;

  // A staging map: thread t -> rows r0+i*16 (i=0..3), 16B k-chunk kq
  const int r0 = tid >> 4;          // 0..15
  const int kq = tid & 15;          // 0..15
  const float* Ap = X + (size_t)(m0 + r0)*Hn + kq*4;
  int awoff[4];
  #pragma unroll
  for (int i=0;i<4;i++){
    int row = r0 + i*16;
    awoff[i] = row*128 + ((kq*8) ^ ((row&7)<<4));
  }

  // B pointers: col = wave*32 + ni*16 + r16, k-base kg*8 (same frags as R3)
  const unsigned short* Bp[2];
  #pragma unroll
  for (int ni=0;ni<2;ni++)
    Bp[ni] = Wt + (size_t)(wave*32 + ni*16 + r16)*Hn + kg*8;

  // A fragment read addrs (identical to R3)
  int abase[4], aswz[4];
  #pragma unroll
  for (int mi=0;mi<4;mi++){
    int row = mi*16 + r16;
    abase[mi] = row*128; aswz[mi] = (row&7)<<4;
  }
  const int kblk = kg*16;

  f32x4 acc[4][2];
  #pragma unroll
  for (int mi=0;mi<4;mi++)
    #pragma unroll
    for (int ni=0;ni<2;ni++) acc[mi][ni] = (f32x4){0.f,0.f,0.f,0.f};

  f32x4  a4[2][4];   // raw A, set parity = step parity of the tile it holds
  bf16x8 bv[2][4];   // B frags [set][ks*2+ni]

  // prologue: A(0)->set0, A(1)->set1, B(0)->set0; write A(0) to buf0
  #pragma unroll
  for (int i=0;i<4;i++) a4[0][i] = *(const f32x4*)(Ap + (size_t)i*16*Hn);
  #pragma unroll
  for (int i=0;i<4;i++) a4[1][i] = *(const f32x4*)(Ap + (size_t)i*16*Hn + 64);
  #pragma unroll
  for (int ks=0;ks<2;ks++)
    #pragma unroll
    for (int ni=0;ni<2;ni++)
      bv[0][ks*2+ni] = *(const bf16x8*)(Bp[ni] + ks*32);
  #pragma unroll
  for (int i=0;i<4;i++){
    s16x4 t;
    t[0]=(short)f2bf(a4[0][i][0]); t[1]=(short)f2bf(a4[0][i][1]);
    t[2]=(short)f2bf(a4[0][i][2]); t[3]=(short)f2bf(a4[0][i][3]);
    *(s16x4*)&sA[0][awoff[i]] = t;
  }
  asm volatile("s_waitcnt lgkmcnt(0)" ::: "memory");
  __builtin_amdgcn_s_barrier();
  __builtin_amdgcn_sched_barrier(0);

  #pragma unroll
  for (int s=0; s<12; ++s){
    const int pb = (s+1)&1;       // compile-time after unroll
    // (1) convert + write A(s+1) (loads issued ~1 step ago; auto vmcnt wait)
    if (s < 11){
      #pragma unroll
      for (int i=0;i<4;i++){
        s16x4 t;
        t[0]=(short)f2bf(a4[pb][i][0]); t[1]=(short)f2bf(a4[pb][i][1]);
        t[2]=(short)f2bf(a4[pb][i][2]); t[3]=(short)f2bf(a4[pb][i][3]);
        *(s16x4*)&sA[pb][awoff[i]] = t;
      }
    }
    // (2) issue A(s+2) and B(s+1) — consumed NEXT step; live across the barrier
    if (s < 10){
      #pragma unroll
      for (int i=0;i<4;i++)
        a4[s&1][i] = *(const f32x4*)(Ap + (size_t)i*16*Hn + (s+2)*64);
    }
    if (s < 11){
      #pragma unroll
      for (int ks=0;ks<2;ks++)
        #pragma unroll
        for (int ni=0;ni<2;ni++)
          bv[pb][ks*2+ni] = *(const bf16x8*)(Bp[ni] + (s+1)*64 + ks*32);
    }
    // (3) compute from sA[s&1] x bv[s&1]  (operand bytes/order == R3)
    #pragma unroll
    for (int ks=0;ks<2;ks++){
      bf16x8 af[4];
      #pragma unroll
      for (int mi=0;mi<4;mi++)
        af[mi] = *(const bf16x8*)&sA[s&1][abase[mi] + ((ks*64 + kblk) ^ aswz[mi])];
      #pragma unroll
      for (int mi=0;mi<4;mi++)
        #pragma unroll
        for (int ni=0;ni<2;ni++)
          acc[mi][ni] = __builtin_amdgcn_mfma_f32_16x16x32_bf16(af[mi], bv[s&1][ks*2+ni], acc[mi][ni], 0, 0, 0);
    }
    // (4) drain LDS ops only (NOT vmcnt) and barrier
    if (s < 11){
      asm volatile("s_waitcnt lgkmcnt(0)" ::: "memory");
      __builtin_amdgcn_s_barrier();
      __builtin_amdgcn_sched_barrier(0);
    }
  }

  // epilogue: C/D layout col=lane&15, row=(lane>>4)*4+r  (m89-verified)
  #pragma unroll
  for (int ni=0;ni<2;ni++){
    int col = wave*32 + ni*16 + r16;
    float bb = bias[col];
    #pragma unroll
    for (int mi=0;mi<4;mi++){
      int row0 = m0 + mi*16 + kg*4;
      #pragma unroll
      for (int r=0;r<4;r++)
        Hout[(size_t)(row0 + r)*Dn + col] = acc[mi][ni][r] + bb;
    }
  }
}

// ---- kernel 2: per-(batch,attr,dim-half) segment mean -> pooled + empty ----
__global__ __launch_bounds__(256) void k_scan(const int* __restrict__ attr,
        const int* __restrict__ item, const float* __restrict__ Hsrc,
        float* __restrict__ pooled, float* __restrict__ empty){
  __shared__ float ssum[4][IT][64];   // 32 KB, one slab per wave
  __shared__ int   slist[4][512];     // 8 KB ordered match lists
  __shared__ int   scnt[IT];

  const int wg  = blockIdx.x;        // (b*8 + a)*2 + dh
  const int dh  = wg & 1;
  const int a   = (wg >> 1) & 7;
  const int b   = wg >> 4;
  const int tid = threadIdx.x;       // 0..255
  const int wv  = tid >> 6;
  const int lane = tid & 63;

  #pragma unroll
  for (int i = 0; i < IT; ++i) ssum[wv][i][lane] = 0.f;
  if (tid < IT) scnt[tid] = 0;

  const int tok0 = wv * 512;
  const int gbase = b * Sn;
  int nm = 0;
  #pragma unroll
  for (int g = 0; g < 8; ++g){
    int tok = tok0 + g*64 + lane;
    int avv = attr[gbase + tok], ivv = item[gbase + tok];
    bool m = (avv == a+1) && (ivv >= 1) && (ivv <= IT);
    unsigned long long mask = __ballot(m);
    int pos = nm + __popcll(mask & ((1ull << lane) - 1ull));
    if (m) slist[wv][pos] = ((ivv-1) << 16) | tok;
    nm += __popcll(mask);
  }
  __syncthreads();   // scnt zeros visible

  for (int e = lane; e < nm; e += 64) atomicAdd(&scnt[slist[wv][e] >> 16], 1);

  const float* hb = Hsrc + (size_t)b*Sn*Dn + dh*64 + lane;
  int e = 0;
  for (; e + 8 <= nm; e += 8){
    int idx[8]; float v[8];
    #pragma unroll
    for (int j=0;j<8;j++) idx[j] = slist[wv][e+j];
    #pragma unroll
    for (int j=0;j<8;j++) v[j] = hb[(size_t)(idx[j] & 0xffff)*Dn];
    #pragma unroll
    for (int j=0;j<8;j++) ssum[wv][idx[j]>>16][lane] += v[j];
  }
  for (; e < nm; ++e){
    int idx = slist[wv][e];
    ssum[wv][idx>>16][lane] += hb[(size_t)(idx & 0xffff)*Dn];
  }
  __syncthreads();

  float* outp = pooled + (size_t)(b*AT + a)*IT*Dn + dh*64;
  for (int o = tid; o < IT*64; o += 256){
    int i = o >> 6, d = o & 63;
    float s = ssum[0][i][d] + ssum[1][i][d] + ssum[2][i][d] + ssum[3][i][d];
    int cnt = scnt[i];
    outp[i*Dn + d] = s / (float)(cnt > 0 ? cnt : 1);
  }
  if (dh == 0 && tid < IT)
    empty[(b*AT + a)*IT + tid] = (scnt[tid] == 0) ? 1.f : 0.f;
}

extern "C" void kernel_launch(void* const* d_in, const int* in_sizes, int n_in,
                              void* d_out, int out_size, void* d_ws, size_t ws_size,
                              hipStream_t stream) {
  const float* hidden = (const float*)d_in[1];
  const int*   attr   = (const int*)  d_in[2];
  const int*   item   = (const int*)  d_in[3];
  const float* W      = (const float*)d_in[4];
  const float* bias   = (const float*)d_in[5];

  float* pooled = (float*)d_out;
  float* empty  = pooled + (size_t)NSEG*Dn;          // +524288
  float* Hout   = empty  + NSEG;                     // +4096

  unsigned short* Wt = (unsigned short*)d_ws;

  k_prep<<<24, 256, 0, stream>>>(W, Wt);
  k_gemm<<<(Bn*Sn)/64, 256, 0, stream>>>(hidden, Wt, bias, Hout);
  k_scan<<<Bn*AT*2, 256, 0, stream>>>(attr, item, Hout, pooled, empty);
}